// Round 15
// baseline (171.784 us; speedup 1.0000x reference)
//
#include <hip/hip_runtime.h>

#define H_DIM 2048
#define EI_DIM 2048
#define NEXP 4
#define BM 144
#define SEG 1152           // rows per expert segment (8 tiles of 144)
#define NROWS 4608         // 4 * 1152 = 32 * 144
#define NTM 32             // row tiles of 144
#define NKB 64             // K blocks of 32
#define NB 16              // 128-col blocks per 2048
#define AFRAG 576          // frags per A k-tile (4 ks * 144 r)
#define WFRAG 512          // frags per weight k-tile (4 ks * 128 c)

typedef __attribute__((ext_vector_type(4))) float f32x4;
typedef __attribute__((ext_vector_type(8))) short bf16x8;
typedef __attribute__((ext_vector_type(4))) short bf16x4;
typedef __attribute__((ext_vector_type(4))) int i32x4;

__device__ __forceinline__ short f2bf(float f) {
  unsigned u = __builtin_bit_cast(unsigned, f);
  u += 0x7fffu + ((u >> 16) & 1u);
  return (short)(u >> 16);
}

__device__ __forceinline__ unsigned pkbf(float lo, float hi) {
  unsigned r;
  asm("v_cvt_pk_bf16_f32 %0, %1, %2" : "=v"(r) : "v"(lo), "v"(hi));
  return r;
}

__device__ __forceinline__ void gload16(const void* g, void* l) {
  __builtin_amdgcn_global_load_lds(
      (const __attribute__((address_space(1))) unsigned*)g,
      (__attribute__((address_space(3))) unsigned*)l, 16, 0, 0);
}

// ---------------- routing: deterministic expert bucketing ----------------
__global__ void route_kernel(const void* __restrict__ token_ids,
                             int* __restrict__ meta, int* __restrict__ row2tok) {
  __shared__ unsigned long long wtot[4];
  const int tid = threadIdx.x;
  const int lane = tid & 63;
  const int wv = tid >> 6;

  for (int i = tid; i < NROWS; i += 256) row2tok[i] = -1;

  const int* ti32 = (const int*)token_ids;
  bool is64 = true;
  for (int i = 0; i < 16; ++i)
    if (ti32[2 * i + 1] != 0) is64 = false;

  const int base = tid * 16;
  unsigned long long pack = 0ULL;
  unsigned eps = 0;
  for (int i = 0; i < 16; ++i) {
    long long v = is64 ? ((const long long*)token_ids)[base + i]
                       : (long long)ti32[base + i];
    if (v < 0) v = 0;
    if (v > 99999) v = 99999;
    int e = (int)(v & 3);
    eps |= (unsigned)e << (2 * i);
    pack += 1ULL << (16 * e);
  }

  unsigned long long incl = pack;
  for (int off = 1; off < 64; off <<= 1) {
    unsigned long long up = __shfl_up(incl, off, 64);
    if (lane >= off) incl += up;
  }
  if (lane == 63) wtot[wv] = incl;
  __syncthreads();

  unsigned long long waveBase = 0;
  for (int w = 0; w < 4; ++w)
    if (w < wv) waveBase += wtot[w];
  const unsigned long long exclu = waveBase + incl - pack;

  if (tid == 0) {
    meta[0] = 36;
    for (int t = 0; t < 36; ++t) meta[1 + t] = t / 9;
  }

  int cur[4];
  for (int e = 0; e < 4; ++e)
    cur[e] = e * SEG + (int)((exclu >> (16 * e)) & 0xffff);
  for (int i = 0; i < 16; ++i) {
    int e = (int)((eps >> (2 * i)) & 3);
    int idx = cur[e]++;
    if (idx < (e + 1) * SEG) row2tok[idx] = base + i;
  }
}

// ======================= FAST PATH (packed layouts) =======================

// convert (Pg, Pu only) + gather fused (grid 4096).
// Blocks 0..2047: weight convert — NT loads + cached stores.
// Blocks 2048..4095: gather permuted X rows.
// Pd conversion lives inside gemm1 (kernel boundary = sync for gemm2).
__global__ __launch_bounds__(256) void convert_gather_kernel(
    const float* __restrict__ gW, const float* __restrict__ uW,
    const float* __restrict__ hidden, const int* __restrict__ row2tok,
    short* __restrict__ Pg, short* __restrict__ Pu, short* __restrict__ xp) {
  __shared__ float Lf[2][2048];  // 2 x 8KB ring (convert role only)
  const int b = blockIdx.x;
  const int tid = threadIdx.x;

  if (b >= 2048) {
    // ---- gather role ----
    const int gb = b - 2048;
    const int tile = gb >> 6;  // 0..31
    const int kb = gb & 63;    // 0..63
    short* db = xp + ((size_t)tile * NKB + kb) * (AFRAG * 8);
#pragma unroll
    for (int q = 0; q < 3; ++q) {
      if (q == 2 && tid >= 64) break;
      const int idx = q * 256 + tid;  // 0..575
      const int ks = idx / 144, r = idx - ks * 144;
      const int tok = row2tok[tile * BM + r];
      bf16x8 v = {0, 0, 0, 0, 0, 0, 0, 0};
      if (tok >= 0) {
        const f32x4* s =
            (const f32x4*)(hidden + (size_t)tok * H_DIM + kb * 32 + ks * 8);
        f32x4 a = s[0], bb = s[1];
        v[0] = f2bf(a[0]); v[1] = f2bf(a[1]); v[2] = f2bf(a[2]); v[3] = f2bf(a[3]);
        v[4] = f2bf(bb[0]); v[5] = f2bf(bb[1]); v[6] = f2bf(bb[2]); v[7] = f2bf(bb[3]);
      }
      *(bf16x8*)(db + idx * 8) = v;
    }
    return;
  }

  // ---- convert role (gate / up) ----
  const int mat = b >> 10;             // 0 = gate, 1 = up
  const int r10 = b & 1023;
  const int e = r10 >> 8;              // 0..3
  const int kb = (r10 >> 3) & 31;      // 0..31
  const int ks = r10 & 7;              // 0..7
  const float* src = mat == 0 ? gW : uW;
  short* dst = mat == 0 ? Pg : Pu;

  const int lr = tid >> 5;             // owned row (0..7)
  const int lc = (tid & 31) * 8;       // owned 8-col group within chunk
  const int wbase = lr * 256 + (lc ^ ((lr & 1) << 2));  // bank-spread write

  const float* lp = src + ((size_t)e * 2048 + kb * 64 + ks * 8 + lr) * 2048 + lc;
  short* doutB = dst + (size_t)(e * 512 + kb) * 8192 + (ks * 128) * 8;

  f32x4 r0[2], r1[2];
  r0[0] = __builtin_nontemporal_load((const f32x4*)lp);
  r1[0] = __builtin_nontemporal_load((const f32x4*)(lp + 4));

#pragma unroll
  for (int q = 0; q < 8; ++q) {
    const int s = q & 1;
    *(f32x4*)&Lf[s][wbase] = r0[s];
    *(f32x4*)&Lf[s][wbase ^ 4] = r1[s];
    if (q < 7) {
      const float* np = lp + (q + 1) * 256;
      r0[s ^ 1] = __builtin_nontemporal_load((const f32x4*)np);
      r1[s ^ 1] = __builtin_nontemporal_load((const f32x4*)(np + 4));
    }
    asm volatile("s_waitcnt lgkmcnt(0)" ::: "memory");
    __builtin_amdgcn_s_barrier();
    __builtin_amdgcn_sched_barrier(0);
    float v[8];
#pragma unroll
    for (int j = 0; j < 8; ++j)
      v[j] = Lf[s][(j * 256 + tid) ^ ((j & 1) << 2)];
    i32x4 w;
    w[0] = pkbf(v[0], v[1]); w[1] = pkbf(v[2], v[3]);
    w[2] = pkbf(v[4], v[5]); w[3] = pkbf(v[6], v[7]);
    const int c = q * 256 + tid;
    const int nb2 = c >> 7, cc = c & 127;
    *(i32x4*)(doutB + (size_t)nb2 * (32 * 8192) + cc * 8) = w;  // cached store
    asm volatile("s_waitcnt lgkmcnt(0)" ::: "memory");
    __builtin_amdgcn_s_barrier();
    __builtin_amdgcn_sched_barrier(0);
  }
}

// GEMM1: fused gate/up + SwiGLU. BM=144, BN=128 (G&U), BK=32.
// 3-deep pipeline, counted vmcnt. ALSO produces this block's 1/512 share of
// packed Pd via T14 split: PROD_ISSUE (NT loads -> regs) BEFORE the stage,
// PROD_WRITE (cvt_pk + stores) AFTER the MFMA block. The register wait is
// vmcnt(7) (only stage ops newer) and the loads hide under a full iteration.
__global__ __launch_bounds__(256, 2) void gemm1_kernel(
    const short* __restrict__ xp, const short* __restrict__ Pg,
    const short* __restrict__ Pu, const float* __restrict__ dW,
    short* __restrict__ Pd, short* __restrict__ inter) {
  const int b0 = blockIdx.x;
  const int swz = (b0 & 7) * 64 + (b0 >> 3);  // 512 blocks, bijective
  const int tile = swz >> 4, nb = swz & 15;
  const int e = tile >> 3;
  // Pd production share: (e2, nb2, g8) covers all 4*16*8 = 512 k-groups
  const int e2 = b0 >> 7, nb2 = (b0 >> 3) & 15, g8 = b0 & 7;

  __shared__ short L[3][12800];  // per buf: A 4608 | G 4096 | U 4096 shorts

  const int tid = threadIdx.x, lane = tid & 63, wv = tid >> 6;
  const int l15 = lane & 15, lks = lane >> 4;
  const int wuni = (tid & 192) * 16;  // wave-uniform byte offset
  const int pc = tid & 127;           // produce: owned column
  const int pksh = tid >> 7;          // produce: ks half

  f32x4 accG[9][2] = {};
  f32x4 accU[9][2] = {};
  float pv[16];                       // produce staging regs (static idx)

  const short* aB = xp + (size_t)(tile * NKB) * (AFRAG * 8);
  const short* gB = Pg + (size_t)((e * NB + nb) * NKB) * (WFRAG * 8);
  const short* uB = Pu + (size_t)((e * NB + nb) * NKB) * (WFRAG * 8);

  // 7 global_load_lds per wave per stage (uniform across waves)
#define STAGE1(kb, bf)                                                        \
  {                                                                           \
    const short* a = aB + (size_t)(kb) * (AFRAG * 8);                         \
    const short* g = gB + (size_t)(kb) * (WFRAG * 8);                         \
    const short* u = uB + (size_t)(kb) * (WFRAG * 8);                         \
    char* la = (char*)&L[bf][0];                                              \
    char* lg = (char*)&L[bf][4608];                                           \
    char* lu = (char*)&L[bf][8704];                                           \
    gload16(a + tid * 8, la + wuni);                                          \
    gload16(a + (256 + tid) * 8, la + 4096 + wuni);                           \
    if (lane < 16)                                                            \
      gload16(a + (512 + wv * 16 + lane) * 8, la + 8192 + wv * 256);          \
    gload16(g + tid * 8, lg + wuni);                                          \
    gload16(g + (256 + tid) * 8, lg + 4096 + wuni);                           \
    gload16(u + tid * 8, lu + wuni);                                          \
    gload16(u + (256 + tid) * 8, lu + 4096 + wuni);                           \
  }

#define PROD_ISSUE(bi)                                                        \
  {                                                                           \
    const int kbp = g8 * 8 + (bi);                                            \
    const float* sb =                                                         \
        dW + ((size_t)e2 * 2048 + kbp * 32) * 2048 + nb2 * 128 + pc;          \
    _Pragma("unroll") for (int k2 = 0; k2 < 2; ++k2) {                        \
      const float* s = sb + (size_t)((pksh * 2 + k2) * 8) * 2048;             \
      _Pragma("unroll") for (int j = 0; j < 8; ++j)                           \
          pv[k2 * 8 + j] = __builtin_nontemporal_load(s + (size_t)j * 2048);  \
    }                                                                         \
  }

#define PROD_WRITE(bi)                                                        \
  {                                                                           \
    const int kbp = g8 * 8 + (bi);                                            \
    short* db =                                                               \
        Pd + ((size_t)((e2 * 16 + nb2) * 64 + kbp)) * 4096 + pc * 8;          \
    _Pragma("unroll") for (int k2 = 0; k2 < 2; ++k2) {                        \
      i32x4 w;                                                                \
      w[0] = pkbf(pv[k2 * 8 + 0], pv[k2 * 8 + 1]);                            \
      w[1] = pkbf(pv[k2 * 8 + 2], pv[k2 * 8 + 3]);                            \
      w[2] = pkbf(pv[k2 * 8 + 4], pv[k2 * 8 + 5]);                            \
      w[3] = pkbf(pv[k2 * 8 + 6], pv[k2 * 8 + 7]);                            \
      *(i32x4*)(db + (pksh * 2 + k2) * 1024) = w;                             \
    }                                                                         \
  }

  STAGE1(0, 0);
  STAGE1(1, 1);

  int bcur = 0;
  int burstIdx = 0, nextBurst = 4, postB = -100;
  for (int kb = 0; kb < NKB; ++kb) {
    if (kb == NKB - 1)
      asm volatile("s_waitcnt vmcnt(0)" ::: "memory");
    else if (kb == postB)
      asm volatile("s_waitcnt vmcnt(9)" ::: "memory");
    else
      asm volatile("s_waitcnt vmcnt(7)" ::: "memory");
    __builtin_amdgcn_s_barrier();
    __builtin_amdgcn_sched_barrier(0);
    const bool burst = (burstIdx < 8 && kb == nextBurst);
    if (burst) {
      PROD_ISSUE(burstIdx);
      __builtin_amdgcn_sched_barrier(0);
    }
    if (kb < NKB - 2) {
      int bn2 = bcur + 2;
      if (bn2 >= 3) bn2 -= 3;
      STAGE1(kb + 2, bn2);
    }
    const short* As = &L[bcur][0];
    const short* Gs = &L[bcur][4608];
    const short* Us = &L[bcur][8704];
    bf16x8 af[9], bg[2], bu[2];
#pragma unroll
    for (int m = 0; m < 9; ++m)
      af[m] = *(const bf16x8*)(As + (lks * 144 + m * 16 + l15) * 8);
#pragma unroll
    for (int n = 0; n < 2; ++n) {
      const int c = wv * 32 + n * 16 + l15;
      bg[n] = *(const bf16x8*)(Gs + (lks * 128 + c) * 8);
      bu[n] = *(const bf16x8*)(Us + (lks * 128 + c) * 8);
    }
    __builtin_amdgcn_s_setprio(1);
#pragma unroll
    for (int m = 0; m < 9; ++m)
#pragma unroll
      for (int n = 0; n < 2; ++n) {
        accG[m][n] = __builtin_amdgcn_mfma_f32_16x16x32_bf16(
            af[m], bg[n], accG[m][n], 0, 0, 0);
        accU[m][n] = __builtin_amdgcn_mfma_f32_16x16x32_bf16(
            af[m], bu[n], accU[m][n], 0, 0, 0);
      }
    __builtin_amdgcn_s_setprio(0);
    if (burst) {
      PROD_WRITE(burstIdx);
      ++burstIdx;
      nextBurst += 6;
      postB = kb + 1;
    }
    if (++bcur == 3) bcur = 0;
  }
#undef STAGE1
#undef PROD_ISSUE
#undef PROD_WRITE

  // epilogue: silu(g)*u -> packed inter [tile][kb2][4 ks][144 r]
#pragma unroll
  for (int n = 0; n < 2; ++n) {
    const int C = nb * 128 + wv * 32 + n * 16 + l15;
    const int kb2 = C >> 5, ks2 = (C >> 3) & 3, kj = C & 7;
    short* ib = inter + (((size_t)tile * NKB + kb2) * AFRAG + ks2 * 144) * 8 + kj;
#pragma unroll
    for (int m = 0; m < 9; ++m)
#pragma unroll
      for (int j = 0; j < 4; ++j) {
        const int r = m * 16 + (lks << 2) + j;
        const float g = accG[m][n][j], u = accU[m][n][j];
        const float s = g / (1.0f + __expf(-g));
        ib[(size_t)r * 8] = f2bf(s * u);
      }
  }
}

// GEMM2: packed inter @ packed down -> scatter fp32 out. BM=144,BN=128,BK=32.
// 3-deep pipeline, counted vmcnt (5 loads/wave/stage). Cached out stores.
__global__ __launch_bounds__(256, 2) void gemm2_kernel(
    const short* __restrict__ inter, const short* __restrict__ Pd,
    const int* __restrict__ row2tok, float* __restrict__ out) {
  const int b0 = blockIdx.x;
  const int swz = (b0 & 7) * 64 + (b0 >> 3);
  const int tile = swz >> 4, nb = swz & 15;
  const int e = tile >> 3;

  __shared__ short L[3][8704];  // per buf: A 4608 | B 4096 shorts

  const int tid = threadIdx.x, lane = tid & 63, wv = tid >> 6;
  const int l15 = lane & 15, lks = lane >> 4;
  const int wuni = (tid & 192) * 16;

  f32x4 acc[9][2] = {};

  const short* aB = inter + (size_t)(tile * NKB) * (AFRAG * 8);
  const short* dB = Pd + (size_t)((e * NB + nb) * NKB) * (WFRAG * 8);

#define STAGE2(kb, bf)                                                        \
  {                                                                           \
    const short* a = aB + (size_t)(kb) * (AFRAG * 8);                         \
    const short* d = dB + (size_t)(kb) * (WFRAG * 8);                         \
    char* la = (char*)&L[bf][0];                                              \
    char* ld = (char*)&L[bf][4608];                                           \
    gload16(a + tid * 8, la + wuni);                                          \
    gload16(a + (256 + tid) * 8, la + 4096 + wuni);                           \
    if (lane < 16)                                                            \
      gload16(a + (512 + wv * 16 + lane) * 8, la + 8192 + wv * 256);          \
    gload16(d + tid * 8, ld + wuni);                                          \
    gload16(d + (256 + tid) * 8, ld + 4096 + wuni);                           \
  }

  STAGE2(0, 0);
  STAGE2(1, 1);

  int bcur = 0;
  for (int kb = 0; kb < NKB; ++kb) {
    if (kb < NKB - 1)
      asm volatile("s_waitcnt vmcnt(5)" ::: "memory");
    else
      asm volatile("s_waitcnt vmcnt(0)" ::: "memory");
    __builtin_amdgcn_s_barrier();
    __builtin_amdgcn_sched_barrier(0);
    if (kb < NKB - 2) {
      int bn2 = bcur + 2;
      if (bn2 >= 3) bn2 -= 3;
      STAGE2(kb + 2, bn2);
    }
    const short* As = &L[bcur][0];
    const short* Bs = &L[bcur][4608];
    bf16x8 af[9], bd[2];
#pragma unroll
    for (int m = 0; m < 9; ++m)
      af[m] = *(const bf16x8*)(As + (lks * 144 + m * 16 + l15) * 8);
#pragma unroll
    for (int n = 0; n < 2; ++n)
      bd[n] = *(const bf16x8*)(Bs + (lks * 128 + wv * 32 + n * 16 + l15) * 8);
    __builtin_amdgcn_s_setprio(1);
#pragma unroll
    for (int m = 0; m < 9; ++m)
#pragma unroll
      for (int n = 0; n < 2; ++n)
        acc[m][n] = __builtin_amdgcn_mfma_f32_16x16x32_bf16(af[m], bd[n],
                                                            acc[m][n], 0, 0, 0);
    __builtin_amdgcn_s_setprio(0);
    if (++bcur == 3) bcur = 0;
  }
#undef STAGE2

#pragma unroll
  for (int m = 0; m < 9; ++m)
#pragma unroll
    for (int j = 0; j < 4; ++j) {
      const int r = tile * BM + m * 16 + (lks << 2) + j;
      const int tok = row2tok[r];
      if (tok >= 0) {
        float* orow = out + (size_t)tok * H_DIM + nb * 128 + wv * 32 + l15;
#pragma unroll
        for (int n = 0; n < 2; ++n) orow[n * 16] = acc[m][n][j];
      }
    }
}

// ======================= FALLBACK (round-1 kernels) =======================

__global__ void gather_fb_kernel(const float* __restrict__ hidden,
                                 const int* __restrict__ row2tok,
                                 short* __restrict__ xperm) {
  const int r = blockIdx.x;
  const int tok = row2tok[r];
  const int tid = threadIdx.x;
  f32x4 a = {0.f, 0.f, 0.f, 0.f}, b = {0.f, 0.f, 0.f, 0.f};
  if (tok >= 0) {
    const f32x4* src = (const f32x4*)(hidden + (size_t)tok * H_DIM + 8 * tid);
    a = src[0];
    b = src[1];
  }
  bf16x8 v;
  v[0] = f2bf(a[0]); v[1] = f2bf(a[1]); v[2] = f2bf(a[2]); v[3] = f2bf(a[3]);
  v[4] = f2bf(b[0]); v[5] = f2bf(b[1]); v[6] = f2bf(b[2]); v[7] = f2bf(b[3]);
  *(bf16x8*)(xperm + (size_t)r * H_DIM + 8 * tid) = v;
}

__global__ __launch_bounds__(256, 2) void gemm1_fb_kernel(
    const short* __restrict__ xperm, const float* __restrict__ gateW,
    const float* __restrict__ upW, const int* __restrict__ meta,
    short* __restrict__ inter) {
  const int tm = blockIdx.x;
  if (tm >= meta[0]) return;
  const int e = meta[1 + tm];
  const int rowBase = tm * 128;
  const int colBase = blockIdx.y * 128;
  const float* gW = gateW + (size_t)e * H_DIM * EI_DIM;
  const float* uW = upW + (size_t)e * H_DIM * EI_DIM;

  __shared__ short As[128 * 64];
  __shared__ short Bg[128 * 64];
  __shared__ short Bu[128 * 64];

  const int tid = threadIdx.x;
  const int lane = tid & 63;
  const int wv = tid >> 6;
  const int wr = (wv >> 1) * 64;
  const int wc = (wv & 1) * 64;

  f32x4 accG[4][4] = {};
  f32x4 accU[4][4] = {};

  const int ar = tid >> 3;
  const int ak = (tid & 7) * 8;
  const int bn = (tid & 31) * 4;
  const int bk = (tid >> 5) * 4;

  for (int k0 = 0; k0 < H_DIM; k0 += 64) {
    bf16x8 av[4];
#pragma unroll
    for (int p = 0; p < 4; ++p) {
      int r = ar + p * 32;
      av[p] = *(const bf16x8*)(xperm + (size_t)(rowBase + r) * H_DIM + k0 + ak);
    }
    f32x4 gv[2][4], uv[2][4];
#pragma unroll
    for (int p = 0; p < 2; ++p) {
      int kk = k0 + bk + p * 32;
#pragma unroll
      for (int i = 0; i < 4; ++i) {
        gv[p][i] = *(const f32x4*)(gW + (size_t)(kk + i) * EI_DIM + colBase + bn);
        uv[p][i] = *(const f32x4*)(uW + (size_t)(kk + i) * EI_DIM + colBase + bn);
      }
    }
    __syncthreads();
#pragma unroll
    for (int p = 0; p < 4; ++p) {
      int r = ar + p * 32;
      int idx = (r * 64 + ak) ^ ((r & 7) << 3);
      *(bf16x8*)(As + idx) = av[p];
    }
#pragma unroll
    for (int p = 0; p < 2; ++p) {
      int kk = bk + p * 32;
#pragma unroll
      for (int j = 0; j < 4; ++j) {
        int rowp = bn + j;
        int idx = (rowp * 64 + kk) ^ ((rowp & 7) << 3);
        bf16x4 vg, vu;
        vg[0] = f2bf(gv[p][0][j]); vg[1] = f2bf(gv[p][1][j]);
        vg[2] = f2bf(gv[p][2][j]); vg[3] = f2bf(gv[p][3][j]);
        vu[0] = f2bf(uv[p][0][j]); vu[1] = f2bf(uv[p][1][j]);
        vu[2] = f2bf(uv[p][2][j]); vu[3] = f2bf(uv[p][3][j]);
        *(bf16x4*)(Bg + idx) = vg;
        *(bf16x4*)(Bu + idx) = vu;
      }
    }
    __syncthreads();
#pragma unroll
    for (int kk = 0; kk < 64; kk += 32) {
      const int kb = kk + ((lane >> 4) << 3);
      bf16x8 af[4], bgf[4], buf_[4];
#pragma unroll
      for (int m = 0; m < 4; ++m) {
        int r = wr + m * 16 + (lane & 15);
        af[m] = *(const bf16x8*)(As + ((r * 64 + kb) ^ ((r & 7) << 3)));
      }
#pragma unroll
      for (int n = 0; n < 4; ++n) {
        int c = wc + n * 16 + (lane & 15);
        int idx = (c * 64 + kb) ^ ((c & 7) << 3);
        bgf[n] = *(const bf16x8*)(Bg + idx);
        buf_[n] = *(const bf16x8*)(Bu + idx);
      }
#pragma unroll
      for (int m = 0; m < 4; ++m)
#pragma unroll
        for (int n = 0; n < 4; ++n) {
          accG[m][n] = __builtin_amdgcn_mfma_f32_16x16x32_bf16(
              af[m], bgf[n], accG[m][n], 0, 0, 0);
          accU[m][n] = __builtin_amdgcn_mfma_f32_16x16x32_bf16(
              af[m], buf_[n], accU[m][n], 0, 0, 0);
        }
    }
  }
#pragma unroll
  for (int m = 0; m < 4; ++m)
#pragma unroll
    for (int n = 0; n < 4; ++n) {
      int c = colBase + wc + n * 16 + (lane & 15);
#pragma unroll
      for (int j = 0; j < 4; ++j) {
        int r = rowBase + wr + m * 16 + ((lane >> 4) << 2) + j;
        float g = accG[m][n][j], u = accU[m][n][j];
        float s = g / (1.0f + __expf(-g));
        inter[(size_t)r * EI_DIM + c] = f2bf(s * u);
      }
    }
}

__global__ __launch_bounds__(256, 2) void gemm2_fb_kernel(
    const short* __restrict__ inter, const float* __restrict__ downW,
    const int* __restrict__ meta, const int* __restrict__ row2tok,
    float* __restrict__ out) {
  const int tm = blockIdx.x;
  if (tm >= meta[0]) return;
  const int e = meta[1 + tm];
  const int rowBase = tm * 128;
  const int colBase = blockIdx.y * 128;
  const float* dW = downW + (size_t)e * EI_DIM * H_DIM;

  __shared__ short As[128 * 64];
  __shared__ short Bs[128 * 64];

  const int tid = threadIdx.x;
  const int lane = tid & 63;
  const int wv = tid >> 6;
  const int wr = (wv >> 1) * 64;
  const int wc = (wv & 1) * 64;

  f32x4 acc[4][4] = {};

  const int ar = tid >> 3;
  const int ak = (tid & 7) * 8;
  const int bn = (tid & 31) * 4;
  const int bk = (tid >> 5) * 4;

  for (int k0 = 0; k0 < EI_DIM; k0 += 64) {
    bf16x8 av[4];
#pragma unroll
    for (int p = 0; p < 4; ++p) {
      int r = ar + p * 32;
      av[p] = *(const bf16x8*)(inter + (size_t)(rowBase + r) * EI_DIM + k0 + ak);
    }
    f32x4 dv[2][4];
#pragma unroll
    for (int p = 0; p < 2; ++p) {
      int kk = k0 + bk + p * 32;
#pragma unroll
      for (int i = 0; i < 4; ++i)
        dv[p][i] = *(const f32x4*)(dW + (size_t)(kk + i) * H_DIM + colBase + bn);
    }
    __syncthreads();
#pragma unroll
    for (int p = 0; p < 4; ++p) {
      int r = ar + p * 32;
      int idx = (r * 64 + ak) ^ ((r & 7) << 3);
      *(bf16x8*)(As + idx) = av[p];
    }
#pragma unroll
    for (int p = 0; p < 2; ++p) {
      int kk = bk + p * 32;
#pragma unroll
      for (int j = 0; j < 4; ++j) {
        int rowp = bn + j;
        int idx = (rowp * 64 + kk) ^ ((rowp & 7) << 3);
        bf16x4 vd;
        vd[0] = f2bf(dv[p][0][j]); vd[1] = f2bf(dv[p][1][j]);
        vd[2] = f2bf(dv[p][2][j]); vd[3] = f2bf(dv[p][3][j]);
        *(bf16x4*)(Bs + idx) = vd;
      }
    }
    __syncthreads();
#pragma unroll
    for (int kk = 0; kk < 64; kk += 32) {
      const int kb = kk + ((lane >> 4) << 3);
      bf16x8 af[4], bf_[4];
#pragma unroll
      for (int m = 0; m < 4; ++m) {
        int r = wr + m * 16 + (lane & 15);
        af[m] = *(const bf16x8*)(As + ((r * 64 + kb) ^ ((r & 7) << 3)));
      }
#pragma unroll
      for (int n = 0; n < 4; ++n) {
        int c = wc + n * 16 + (lane & 15);
        bf_[n] = *(const bf16x8*)(Bs + ((c * 64 + kb) ^ ((c & 7) << 3)));
      }
#pragma unroll
      for (int m = 0; m < 4; ++m)
#pragma unroll
        for (int n = 0; n < 4; ++n)
          acc[m][n] = __builtin_amdgcn_mfma_f32_16x16x32_bf16(
              af[m], bf_[n], acc[m][n], 0, 0, 0);
    }
  }
#pragma unroll
  for (int m = 0; m < 4; ++m)
#pragma unroll
    for (int j = 0; j < 4; ++j) {
      int r = rowBase + wr + m * 16 + ((lane >> 4) << 2) + j;
      int tok = row2tok[r];
      if (tok >= 0) {
        float* orow = out + (size_t)tok * H_DIM + colBase + wc + (lane & 15);
#pragma unroll
        for (int n = 0; n < 4; ++n) orow[n * 16] = acc[m][n][j];
      }
    }
}

// ======================= launch =======================

extern "C" void kernel_launch(void* const* d_in, const int* in_sizes, int n_in,
                              void* d_out, int out_size, void* d_ws,
                              size_t ws_size, hipStream_t stream) {
  const float* hidden = (const float*)d_in[0];
  const void* token_ids = d_in[1];
  const float* gateW = (const float*)d_in[2];
  const float* upW = (const float*)d_in[3];
  const float* downW = (const float*)d_in[4];
  float* out = (float*)d_out;

  int* meta = (int*)d_ws;
  int* row2tok = meta + 64;

  const size_t wMatShorts = (size_t)NEXP * NB * 32 * 8192;       // 16.78M
  const size_t xpShorts = (size_t)NTM * NKB * AFRAG * 8;         // 9.44M
  const size_t need = 32768 + 3 * wMatShorts * 2 + 2 * xpShorts * 2;

  route_kernel<<<1, 256, 0, stream>>>(token_ids, meta, row2tok);

  if (ws_size >= need) {
    short* Pg = (short*)((char*)d_ws + 32768);
    short* Pu = Pg + wMatShorts;
    short* Pd = Pu + wMatShorts;
    short* xp = Pd + wMatShorts;
    short* inter = xp + xpShorts;

    convert_gather_kernel<<<4096, 256, 0, stream>>>(gateW, upW, hidden,
                                                    row2tok, Pg, Pu, xp);
    gemm1_kernel<<<512, 256, 0, stream>>>(xp, Pg, Pu, downW, Pd, inter);
    gemm2_kernel<<<512, 256, 0, stream>>>(inter, Pd, row2tok, out);
  } else {
    short* xperm = (short*)((char*)d_ws + 32768);
    short* inter = xperm + (size_t)NROWS * H_DIM;

    gather_fb_kernel<<<NROWS, 256, 0, stream>>>(hidden, row2tok, xperm);
    gemm1_fb_kernel<<<dim3(36, EI_DIM / 128), 256, 0, stream>>>(
        xperm, gateW, upW, meta, inter);
    gemm2_fb_kernel<<<dim3(36, H_DIM / 128), 256, 0, stream>>>(
        inter, downW, meta, row2tok, out);
  }
}

// Round 16
// 170.458 us; speedup vs baseline: 1.0078x; 1.0078x over previous
//
#include <hip/hip_runtime.h>

#define H_DIM 2048
#define EI_DIM 2048
#define NEXP 4
#define BM 144
#define SEG 1152           // rows per expert segment (8 tiles of 144)
#define NROWS 4608         // 4 * 1152 = 32 * 144
#define NTM 32             // row tiles of 144
#define NKB 64             // K blocks of 32
#define NB 16              // 128-col blocks per 2048
#define AFRAG 576          // frags per A k-tile (4 ks * 144 r)
#define WFRAG 512          // frags per weight k-tile (4 ks * 128 c)

typedef __attribute__((ext_vector_type(4))) float f32x4;
typedef __attribute__((ext_vector_type(8))) short bf16x8;
typedef __attribute__((ext_vector_type(4))) short bf16x4;
typedef __attribute__((ext_vector_type(4))) int i32x4;

__device__ __forceinline__ short f2bf(float f) {
  unsigned u = __builtin_bit_cast(unsigned, f);
  u += 0x7fffu + ((u >> 16) & 1u);
  return (short)(u >> 16);
}

__device__ __forceinline__ unsigned pkbf(float lo, float hi) {
  unsigned r;
  asm("v_cvt_pk_bf16_f32 %0, %1, %2" : "=v"(r) : "v"(lo), "v"(hi));
  return r;
}

__device__ __forceinline__ void gload16(const void* g, void* l) {
  __builtin_amdgcn_global_load_lds(
      (const __attribute__((address_space(1))) unsigned*)g,
      (__attribute__((address_space(3))) unsigned*)l, 16, 0, 0);
}

// convert ONE kb-tile (32 K-rows x 128 cols) of a fp32 weight panel into a
// packed bf16 fragment tile. NT loads (read-once), cached stores (reused).
__device__ __forceinline__ void produce_wtile(const float* __restrict__ W,
                                              short* __restrict__ P, int e,
                                              int nb, int kb, int tid) {
  const int c = tid & 127;   // owned column
  const int ksh = tid >> 7;  // 0..1 -> ks pair
  const float* sb = W + ((size_t)e * 2048 + kb * 32) * 2048 + nb * 128 + c;
  short* db = P + ((size_t)((e * 16 + nb) * 64 + kb)) * 4096 + c * 8;
#pragma unroll
  for (int k2 = 0; k2 < 2; ++k2) {
    const int ks = ksh * 2 + k2;
    const float* s = sb + (size_t)(ks * 8) * 2048;
    float v[8];
#pragma unroll
    for (int j = 0; j < 8; ++j)
      v[j] = __builtin_nontemporal_load(s + (size_t)j * 2048);
    i32x4 w;
    w[0] = pkbf(v[0], v[1]); w[1] = pkbf(v[2], v[3]);
    w[2] = pkbf(v[4], v[5]); w[3] = pkbf(v[6], v[7]);
    *(i32x4*)(db + ks * 1024) = w;
  }
}

// ---------------- routing: deterministic expert bucketing ----------------
__global__ void route_kernel(const void* __restrict__ token_ids,
                             int* __restrict__ meta, int* __restrict__ row2tok) {
  __shared__ unsigned long long wtot[4];
  const int tid = threadIdx.x;
  const int lane = tid & 63;
  const int wv = tid >> 6;

  for (int i = tid; i < NROWS; i += 256) row2tok[i] = -1;

  const int* ti32 = (const int*)token_ids;
  bool is64 = true;
  for (int i = 0; i < 16; ++i)
    if (ti32[2 * i + 1] != 0) is64 = false;

  const int base = tid * 16;
  unsigned long long pack = 0ULL;
  unsigned eps = 0;
  for (int i = 0; i < 16; ++i) {
    long long v = is64 ? ((const long long*)token_ids)[base + i]
                       : (long long)ti32[base + i];
    if (v < 0) v = 0;
    if (v > 99999) v = 99999;
    int e = (int)(v & 3);
    eps |= (unsigned)e << (2 * i);
    pack += 1ULL << (16 * e);
  }

  unsigned long long incl = pack;
  for (int off = 1; off < 64; off <<= 1) {
    unsigned long long up = __shfl_up(incl, off, 64);
    if (lane >= off) incl += up;
  }
  if (lane == 63) wtot[wv] = incl;
  __syncthreads();

  unsigned long long waveBase = 0;
  for (int w = 0; w < 4; ++w)
    if (w < wv) waveBase += wtot[w];
  const unsigned long long exclu = waveBase + incl - pack;

  if (tid == 0) {
    meta[0] = 36;
    for (int t = 0; t < 36; ++t) meta[1 + t] = t / 9;
  }

  int cur[4];
  for (int e = 0; e < 4; ++e)
    cur[e] = e * SEG + (int)((exclu >> (16 * e)) & 0xffff);
  for (int i = 0; i < 16; ++i) {
    int e = (int)((eps >> (2 * i)) & 3);
    int idx = cur[e]++;
    if (idx < (e + 1) * SEG) row2tok[idx] = base + i;
  }
}

// ======================= FAST PATH (packed layouts) =======================

// convert (Pg, Pu only) + gather fused (grid 4096).
// Blocks 0..2047: weight convert — NT loads + cached stores.
// Blocks 2048..4095: gather permuted X rows.
// Pd conversion lives inside gemm1 (kernel boundary = sync for gemm2).
__global__ __launch_bounds__(256) void convert_gather_kernel(
    const float* __restrict__ gW, const float* __restrict__ uW,
    const float* __restrict__ hidden, const int* __restrict__ row2tok,
    short* __restrict__ Pg, short* __restrict__ Pu, short* __restrict__ xp) {
  __shared__ float Lf[2][2048];  // 2 x 8KB ring (convert role only)
  const int b = blockIdx.x;
  const int tid = threadIdx.x;

  if (b >= 2048) {
    // ---- gather role ----
    const int gb = b - 2048;
    const int tile = gb >> 6;  // 0..31
    const int kb = gb & 63;    // 0..63
    short* db = xp + ((size_t)tile * NKB + kb) * (AFRAG * 8);
#pragma unroll
    for (int q = 0; q < 3; ++q) {
      if (q == 2 && tid >= 64) break;
      const int idx = q * 256 + tid;  // 0..575
      const int ks = idx / 144, r = idx - ks * 144;
      const int tok = row2tok[tile * BM + r];
      bf16x8 v = {0, 0, 0, 0, 0, 0, 0, 0};
      if (tok >= 0) {
        const f32x4* s =
            (const f32x4*)(hidden + (size_t)tok * H_DIM + kb * 32 + ks * 8);
        f32x4 a = s[0], bb = s[1];
        v[0] = f2bf(a[0]); v[1] = f2bf(a[1]); v[2] = f2bf(a[2]); v[3] = f2bf(a[3]);
        v[4] = f2bf(bb[0]); v[5] = f2bf(bb[1]); v[6] = f2bf(bb[2]); v[7] = f2bf(bb[3]);
      }
      *(bf16x8*)(db + idx * 8) = v;
    }
    return;
  }

  // ---- convert role (gate / up) ----
  const int mat = b >> 10;             // 0 = gate, 1 = up
  const int r10 = b & 1023;
  const int e = r10 >> 8;              // 0..3
  const int kb = (r10 >> 3) & 31;      // 0..31
  const int ks = r10 & 7;              // 0..7
  const float* src = mat == 0 ? gW : uW;
  short* dst = mat == 0 ? Pg : Pu;

  const int lr = tid >> 5;             // owned row (0..7)
  const int lc = (tid & 31) * 8;       // owned 8-col group within chunk
  const int wbase = lr * 256 + (lc ^ ((lr & 1) << 2));  // bank-spread write

  const float* lp = src + ((size_t)e * 2048 + kb * 64 + ks * 8 + lr) * 2048 + lc;
  short* doutB = dst + (size_t)(e * 512 + kb) * 8192 + (ks * 128) * 8;

  f32x4 r0[2], r1[2];
  r0[0] = __builtin_nontemporal_load((const f32x4*)lp);
  r1[0] = __builtin_nontemporal_load((const f32x4*)(lp + 4));

#pragma unroll
  for (int q = 0; q < 8; ++q) {
    const int s = q & 1;
    *(f32x4*)&Lf[s][wbase] = r0[s];
    *(f32x4*)&Lf[s][wbase ^ 4] = r1[s];
    if (q < 7) {
      const float* np = lp + (q + 1) * 256;
      r0[s ^ 1] = __builtin_nontemporal_load((const f32x4*)np);
      r1[s ^ 1] = __builtin_nontemporal_load((const f32x4*)(np + 4));
    }
    asm volatile("s_waitcnt lgkmcnt(0)" ::: "memory");
    __builtin_amdgcn_s_barrier();
    __builtin_amdgcn_sched_barrier(0);
    float v[8];
#pragma unroll
    for (int j = 0; j < 8; ++j)
      v[j] = Lf[s][(j * 256 + tid) ^ ((j & 1) << 2)];
    i32x4 w;
    w[0] = pkbf(v[0], v[1]); w[1] = pkbf(v[2], v[3]);
    w[2] = pkbf(v[4], v[5]); w[3] = pkbf(v[6], v[7]);
    const int c = q * 256 + tid;
    const int nb2 = c >> 7, cc = c & 127;
    *(i32x4*)(doutB + (size_t)nb2 * (32 * 8192) + cc * 8) = w;  // cached store
    asm volatile("s_waitcnt lgkmcnt(0)" ::: "memory");
    __builtin_amdgcn_s_barrier();
    __builtin_amdgcn_sched_barrier(0);
  }
}

// GEMM1: fused gate/up + SwiGLU. BM=144, BN=128 (G&U), BK=32.
// 3-deep pipeline, counted vmcnt. ALSO produces this block's 1/512 share of
// packed Pd (8 kb-tiles, one per burst at kb=4,8,..,32) — traffic hides
// under MFMA; gemm2 (next kernel) consumes it. vmcnt safety: vmcnt(N) after
// issuing N stage loads guarantees all OLDER ops (incl. produce) drained.
__global__ __launch_bounds__(256, 2) void gemm1_kernel(
    const short* __restrict__ xp, const short* __restrict__ Pg,
    const short* __restrict__ Pu, const float* __restrict__ dW,
    short* __restrict__ Pd, short* __restrict__ inter) {
  const int b0 = blockIdx.x;
  const int swz = (b0 & 7) * 64 + (b0 >> 3);  // 512 blocks, bijective
  const int tile = swz >> 4, nb = swz & 15;
  const int e = tile >> 3;
  // Pd production share: (e2, nb2, g8) covers all 4*16*8 = 512 k-groups
  const int e2 = b0 >> 7, nb2 = (b0 >> 3) & 15, g8 = b0 & 7;

  __shared__ short L[3][12800];  // per buf: A 4608 | G 4096 | U 4096 shorts

  const int tid = threadIdx.x, lane = tid & 63, wv = tid >> 6;
  const int l15 = lane & 15, lks = lane >> 4;
  const int wuni = (tid & 192) * 16;  // wave-uniform byte offset

  f32x4 accG[9][2] = {};
  f32x4 accU[9][2] = {};

  const short* aB = xp + (size_t)(tile * NKB) * (AFRAG * 8);
  const short* gB = Pg + (size_t)((e * NB + nb) * NKB) * (WFRAG * 8);
  const short* uB = Pu + (size_t)((e * NB + nb) * NKB) * (WFRAG * 8);

  // 7 global_load_lds per wave per stage (uniform across waves)
#define STAGE1(kb, bf)                                                        \
  {                                                                           \
    const short* a = aB + (size_t)(kb) * (AFRAG * 8);                         \
    const short* g = gB + (size_t)(kb) * (WFRAG * 8);                         \
    const short* u = uB + (size_t)(kb) * (WFRAG * 8);                         \
    char* la = (char*)&L[bf][0];                                              \
    char* lg = (char*)&L[bf][4608];                                           \
    char* lu = (char*)&L[bf][8704];                                           \
    gload16(a + tid * 8, la + wuni);                                          \
    gload16(a + (256 + tid) * 8, la + 4096 + wuni);                           \
    if (lane < 16)                                                            \
      gload16(a + (512 + wv * 16 + lane) * 8, la + 8192 + wv * 256);          \
    gload16(g + tid * 8, lg + wuni);                                          \
    gload16(g + (256 + tid) * 8, lg + 4096 + wuni);                           \
    gload16(u + tid * 8, lu + wuni);                                          \
    gload16(u + (256 + tid) * 8, lu + 4096 + wuni);                           \
  }

  STAGE1(0, 0);
  STAGE1(1, 1);

  int bcur = 0;
  for (int kb = 0; kb < NKB; ++kb) {
    if (kb < NKB - 1)
      asm volatile("s_waitcnt vmcnt(7)" ::: "memory");
    else
      asm volatile("s_waitcnt vmcnt(0)" ::: "memory");
    __builtin_amdgcn_s_barrier();
    __builtin_amdgcn_sched_barrier(0);
    // staggered Pd production (block-uniform; one kb-tile per burst)
    if ((kb & 3) == 0 && kb >= 4 && kb <= 32) {
      produce_wtile(dW, Pd, e2, nb2, g8 * 8 + ((kb >> 2) - 1), tid);
      __builtin_amdgcn_sched_barrier(0);
    }
    if (kb < NKB - 2) {
      int bn2 = bcur + 2;
      if (bn2 >= 3) bn2 -= 3;
      STAGE1(kb + 2, bn2);
    }
    const short* As = &L[bcur][0];
    const short* Gs = &L[bcur][4608];
    const short* Us = &L[bcur][8704];
    bf16x8 af[9], bg[2], bu[2];
#pragma unroll
    for (int m = 0; m < 9; ++m)
      af[m] = *(const bf16x8*)(As + (lks * 144 + m * 16 + l15) * 8);
#pragma unroll
    for (int n = 0; n < 2; ++n) {
      const int c = wv * 32 + n * 16 + l15;
      bg[n] = *(const bf16x8*)(Gs + (lks * 128 + c) * 8);
      bu[n] = *(const bf16x8*)(Us + (lks * 128 + c) * 8);
    }
    __builtin_amdgcn_s_setprio(1);
#pragma unroll
    for (int m = 0; m < 9; ++m)
#pragma unroll
      for (int n = 0; n < 2; ++n) {
        accG[m][n] = __builtin_amdgcn_mfma_f32_16x16x32_bf16(
            af[m], bg[n], accG[m][n], 0, 0, 0);
        accU[m][n] = __builtin_amdgcn_mfma_f32_16x16x32_bf16(
            af[m], bu[n], accU[m][n], 0, 0, 0);
      }
    __builtin_amdgcn_s_setprio(0);
    if (++bcur == 3) bcur = 0;
  }
#undef STAGE1

  // epilogue: silu(g)*u -> packed inter [tile][kb2][4 ks][144 r]
#pragma unroll
  for (int n = 0; n < 2; ++n) {
    const int C = nb * 128 + wv * 32 + n * 16 + l15;
    const int kb2 = C >> 5, ks2 = (C >> 3) & 3, kj = C & 7;
    short* ib = inter + (((size_t)tile * NKB + kb2) * AFRAG + ks2 * 144) * 8 + kj;
#pragma unroll
    for (int m = 0; m < 9; ++m)
#pragma unroll
      for (int j = 0; j < 4; ++j) {
        const int r = m * 16 + (lks << 2) + j;
        const float g = accG[m][n][j], u = accU[m][n][j];
        const float s = g / (1.0f + __expf(-g));
        ib[(size_t)r * 8] = f2bf(s * u);
      }
  }
}

// GEMM2: packed inter @ packed down -> scatter fp32 out. BM=144,BN=128,BK=32.
// 3-deep pipeline, counted vmcnt (5 loads/wave/stage). Cached out stores.
__global__ __launch_bounds__(256, 2) void gemm2_kernel(
    const short* __restrict__ inter, const short* __restrict__ Pd,
    const int* __restrict__ row2tok, float* __restrict__ out) {
  const int b0 = blockIdx.x;
  const int swz = (b0 & 7) * 64 + (b0 >> 3);
  const int tile = swz >> 4, nb = swz & 15;
  const int e = tile >> 3;

  __shared__ short L[3][8704];  // per buf: A 4608 | B 4096 shorts

  const int tid = threadIdx.x, lane = tid & 63, wv = tid >> 6;
  const int l15 = lane & 15, lks = lane >> 4;
  const int wuni = (tid & 192) * 16;

  f32x4 acc[9][2] = {};

  const short* aB = inter + (size_t)(tile * NKB) * (AFRAG * 8);
  const short* dB = Pd + (size_t)((e * NB + nb) * NKB) * (WFRAG * 8);

#define STAGE2(kb, bf)                                                        \
  {                                                                           \
    const short* a = aB + (size_t)(kb) * (AFRAG * 8);                         \
    const short* d = dB + (size_t)(kb) * (WFRAG * 8);                         \
    char* la = (char*)&L[bf][0];                                              \
    char* ld = (char*)&L[bf][4608];                                           \
    gload16(a + tid * 8, la + wuni);                                          \
    gload16(a + (256 + tid) * 8, la + 4096 + wuni);                           \
    if (lane < 16)                                                            \
      gload16(a + (512 + wv * 16 + lane) * 8, la + 8192 + wv * 256);          \
    gload16(d + tid * 8, ld + wuni);                                          \
    gload16(d + (256 + tid) * 8, ld + 4096 + wuni);                           \
  }

  STAGE2(0, 0);
  STAGE2(1, 1);

  int bcur = 0;
  for (int kb = 0; kb < NKB; ++kb) {
    if (kb < NKB - 1)
      asm volatile("s_waitcnt vmcnt(5)" ::: "memory");
    else
      asm volatile("s_waitcnt vmcnt(0)" ::: "memory");
    __builtin_amdgcn_s_barrier();
    __builtin_amdgcn_sched_barrier(0);
    if (kb < NKB - 2) {
      int bn2 = bcur + 2;
      if (bn2 >= 3) bn2 -= 3;
      STAGE2(kb + 2, bn2);
    }
    const short* As = &L[bcur][0];
    const short* Bs = &L[bcur][4608];
    bf16x8 af[9], bd[2];
#pragma unroll
    for (int m = 0; m < 9; ++m)
      af[m] = *(const bf16x8*)(As + (lks * 144 + m * 16 + l15) * 8);
#pragma unroll
    for (int n = 0; n < 2; ++n)
      bd[n] = *(const bf16x8*)(Bs + (lks * 128 + wv * 32 + n * 16 + l15) * 8);
    __builtin_amdgcn_s_setprio(1);
#pragma unroll
    for (int m = 0; m < 9; ++m)
#pragma unroll
      for (int n = 0; n < 2; ++n)
        acc[m][n] = __builtin_amdgcn_mfma_f32_16x16x32_bf16(af[m], bd[n],
                                                            acc[m][n], 0, 0, 0);
    __builtin_amdgcn_s_setprio(0);
    if (++bcur == 3) bcur = 0;
  }
#undef STAGE2

#pragma unroll
  for (int m = 0; m < 9; ++m)
#pragma unroll
    for (int j = 0; j < 4; ++j) {
      const int r = tile * BM + m * 16 + (lks << 2) + j;
      const int tok = row2tok[r];
      if (tok >= 0) {
        float* orow = out + (size_t)tok * H_DIM + nb * 128 + wv * 32 + l15;
#pragma unroll
        for (int n = 0; n < 2; ++n) orow[n * 16] = acc[m][n][j];
      }
    }
}

// ======================= FALLBACK (round-1 kernels) =======================

__global__ void gather_fb_kernel(const float* __restrict__ hidden,
                                 const int* __restrict__ row2tok,
                                 short* __restrict__ xperm) {
  const int r = blockIdx.x;
  const int tok = row2tok[r];
  const int tid = threadIdx.x;
  f32x4 a = {0.f, 0.f, 0.f, 0.f}, b = {0.f, 0.f, 0.f, 0.f};
  if (tok >= 0) {
    const f32x4* src = (const f32x4*)(hidden + (size_t)tok * H_DIM + 8 * tid);
    a = src[0];
    b = src[1];
  }
  bf16x8 v;
  v[0] = f2bf(a[0]); v[1] = f2bf(a[1]); v[2] = f2bf(a[2]); v[3] = f2bf(a[3]);
  v[4] = f2bf(b[0]); v[5] = f2bf(b[1]); v[6] = f2bf(b[2]); v[7] = f2bf(b[3]);
  *(bf16x8*)(xperm + (size_t)r * H_DIM + 8 * tid) = v;
}

__global__ __launch_bounds__(256, 2) void gemm1_fb_kernel(
    const short* __restrict__ xperm, const float* __restrict__ gateW,
    const float* __restrict__ upW, const int* __restrict__ meta,
    short* __restrict__ inter) {
  const int tm = blockIdx.x;
  if (tm >= meta[0]) return;
  const int e = meta[1 + tm];
  const int rowBase = tm * 128;
  const int colBase = blockIdx.y * 128;
  const float* gW = gateW + (size_t)e * H_DIM * EI_DIM;
  const float* uW = upW + (size_t)e * H_DIM * EI_DIM;

  __shared__ short As[128 * 64];
  __shared__ short Bg[128 * 64];
  __shared__ short Bu[128 * 64];

  const int tid = threadIdx.x;
  const int lane = tid & 63;
  const int wv = tid >> 6;
  const int wr = (wv >> 1) * 64;
  const int wc = (wv & 1) * 64;

  f32x4 accG[4][4] = {};
  f32x4 accU[4][4] = {};

  const int ar = tid >> 3;
  const int ak = (tid & 7) * 8;
  const int bn = (tid & 31) * 4;
  const int bk = (tid >> 5) * 4;

  for (int k0 = 0; k0 < H_DIM; k0 += 64) {
    bf16x8 av[4];
#pragma unroll
    for (int p = 0; p < 4; ++p) {
      int r = ar + p * 32;
      av[p] = *(const bf16x8*)(xperm + (size_t)(rowBase + r) * H_DIM + k0 + ak);
    }
    f32x4 gv[2][4], uv[2][4];
#pragma unroll
    for (int p = 0; p < 2; ++p) {
      int kk = k0 + bk + p * 32;
#pragma unroll
      for (int i = 0; i < 4; ++i) {
        gv[p][i] = *(const f32x4*)(gW + (size_t)(kk + i) * EI_DIM + colBase + bn);
        uv[p][i] = *(const f32x4*)(uW + (size_t)(kk + i) * EI_DIM + colBase + bn);
      }
    }
    __syncthreads();
#pragma unroll
    for (int p = 0; p < 4; ++p) {
      int r = ar + p * 32;
      int idx = (r * 64 + ak) ^ ((r & 7) << 3);
      *(bf16x8*)(As + idx) = av[p];
    }
#pragma unroll
    for (int p = 0; p < 2; ++p) {
      int kk = bk + p * 32;
#pragma unroll
      for (int j = 0; j < 4; ++j) {
        int rowp = bn + j;
        int idx = (rowp * 64 + kk) ^ ((rowp & 7) << 3);
        bf16x4 vg, vu;
        vg[0] = f2bf(gv[p][0][j]); vg[1] = f2bf(gv[p][1][j]);
        vg[2] = f2bf(gv[p][2][j]); vg[3] = f2bf(gv[p][3][j]);
        vu[0] = f2bf(uv[p][0][j]); vu[1] = f2bf(uv[p][1][j]);
        vu[2] = f2bf(uv[p][2][j]); vu[3] = f2bf(uv[p][3][j]);
        *(bf16x4*)(Bg + idx) = vg;
        *(bf16x4*)(Bu + idx) = vu;
      }
    }
    __syncthreads();
#pragma unroll
    for (int kk = 0; kk < 64; kk += 32) {
      const int kb = kk + ((lane >> 4) << 3);
      bf16x8 af[4], bgf[4], buf_[4];
#pragma unroll
      for (int m = 0; m < 4; ++m) {
        int r = wr + m * 16 + (lane & 15);
        af[m] = *(const bf16x8*)(As + ((r * 64 + kb) ^ ((r & 7) << 3)));
      }
#pragma unroll
      for (int n = 0; n < 4; ++n) {
        int c = wc + n * 16 + (lane & 15);
        int idx = (c * 64 + kb) ^ ((c & 7) << 3);
        bgf[n] = *(const bf16x8*)(Bg + idx);
        buf_[n] = *(const bf16x8*)(Bu + idx);
      }
#pragma unroll
      for (int m = 0; m < 4; ++m)
#pragma unroll
        for (int n = 0; n < 4; ++n) {
          accG[m][n] = __builtin_amdgcn_mfma_f32_16x16x32_bf16(
              af[m], bgf[n], accG[m][n], 0, 0, 0);
          accU[m][n] = __builtin_amdgcn_mfma_f32_16x16x32_bf16(
              af[m], buf_[n], accU[m][n], 0, 0, 0);
        }
    }
  }
#pragma unroll
  for (int m = 0; m < 4; ++m)
#pragma unroll
    for (int n = 0; n < 4; ++n) {
      int c = colBase + wc + n * 16 + (lane & 15);
#pragma unroll
      for (int j = 0; j < 4; ++j) {
        int r = rowBase + wr + m * 16 + ((lane >> 4) << 2) + j;
        float g = accG[m][n][j], u = accU[m][n][j];
        float s = g / (1.0f + __expf(-g));
        inter[(size_t)r * EI_DIM + c] = f2bf(s * u);
      }
    }
}

__global__ __launch_bounds__(256, 2) void gemm2_fb_kernel(
    const short* __restrict__ inter, const float* __restrict__ downW,
    const int* __restrict__ meta, const int* __restrict__ row2tok,
    float* __restrict__ out) {
  const int tm = blockIdx.x;
  if (tm >= meta[0]) return;
  const int e = meta[1 + tm];
  const int rowBase = tm * 128;
  const int colBase = blockIdx.y * 128;
  const float* dW = downW + (size_t)e * EI_DIM * H_DIM;

  __shared__ short As[128 * 64];
  __shared__ short Bs[128 * 64];

  const int tid = threadIdx.x;
  const int lane = tid & 63;
  const int wv = tid >> 6;
  const int wr = (wv >> 1) * 64;
  const int wc = (wv & 1) * 64;

  f32x4 acc[4][4] = {};

  const int ar = tid >> 3;
  const int ak = (tid & 7) * 8;
  const int bn = (tid & 31) * 4;
  const int bk = (tid >> 5) * 4;

  for (int k0 = 0; k0 < EI_DIM; k0 += 64) {
    bf16x8 av[4];
#pragma unroll
    for (int p = 0; p < 4; ++p) {
      int r = ar + p * 32;
      av[p] = *(const bf16x8*)(inter + (size_t)(rowBase + r) * EI_DIM + k0 + ak);
    }
    f32x4 dv[2][4];
#pragma unroll
    for (int p = 0; p < 2; ++p) {
      int kk = k0 + bk + p * 32;
#pragma unroll
      for (int i = 0; i < 4; ++i)
        dv[p][i] = *(const f32x4*)(dW + (size_t)(kk + i) * H_DIM + colBase + bn);
    }
    __syncthreads();
#pragma unroll
    for (int p = 0; p < 4; ++p) {
      int r = ar + p * 32;
      int idx = (r * 64 + ak) ^ ((r & 7) << 3);
      *(bf16x8*)(As + idx) = av[p];
    }
#pragma unroll
    for (int p = 0; p < 2; ++p) {
      int kk = bk + p * 32;
#pragma unroll
      for (int j = 0; j < 4; ++j) {
        int rowp = bn + j;
        int idx = (rowp * 64 + kk) ^ ((rowp & 7) << 3);
        bf16x4 vd;
        vd[0] = f2bf(dv[p][0][j]); vd[1] = f2bf(dv[p][1][j]);
        vd[2] = f2bf(dv[p][2][j]); vd[3] = f2bf(dv[p][3][j]);
        *(bf16x4*)(Bs + idx) = vd;
      }
    }
    __syncthreads();
#pragma unroll
    for (int kk = 0; kk < 64; kk += 32) {
      const int kb = kk + ((lane >> 4) << 3);
      bf16x8 af[4], bf_[4];
#pragma unroll
      for (int m = 0; m < 4; ++m) {
        int r = wr + m * 16 + (lane & 15);
        af[m] = *(const bf16x8*)(As + ((r * 64 + kb) ^ ((r & 7) << 3)));
      }
#pragma unroll
      for (int n = 0; n < 4; ++n) {
        int c = wc + n * 16 + (lane & 15);
        bf_[n] = *(const bf16x8*)(Bs + ((c * 64 + kb) ^ ((c & 7) << 3)));
      }
#pragma unroll
      for (int m = 0; m < 4; ++m)
#pragma unroll
        for (int n = 0; n < 4; ++n)
          acc[m][n] = __builtin_amdgcn_mfma_f32_16x16x32_bf16(
              af[m], bf_[n], acc[m][n], 0, 0, 0);
    }
  }
#pragma unroll
  for (int m = 0; m < 4; ++m)
#pragma unroll
    for (int j = 0; j < 4; ++j) {
      int r = rowBase + wr + m * 16 + ((lane >> 4) << 2) + j;
      int tok = row2tok[r];
      if (tok >= 0) {
        float* orow = out + (size_t)tok * H_DIM + colBase + wc + (lane & 15);
#pragma unroll
        for (int n = 0; n < 4; ++n) orow[n * 16] = acc[m][n][j];
      }
    }
}

// ======================= launch =======================

extern "C" void kernel_launch(void* const* d_in, const int* in_sizes, int n_in,
                              void* d_out, int out_size, void* d_ws,
                              size_t ws_size, hipStream_t stream) {
  const float* hidden = (const float*)d_in[0];
  const void* token_ids = d_in[1];
  const float* gateW = (const float*)d_in[2];
  const float* upW = (const float*)d_in[3];
  const float* downW = (const float*)d_in[4];
  float* out = (float*)d_out;

  int* meta = (int*)d_ws;
  int* row2tok = meta + 64;

  const size_t wMatShorts = (size_t)NEXP * NB * 32 * 8192;       // 16.78M
  const size_t xpShorts = (size_t)NTM * NKB * AFRAG * 8;         // 9.44M
  const size_t need = 32768 + 3 * wMatShorts * 2 + 2 * xpShorts * 2;

  route_kernel<<<1, 256, 0, stream>>>(token_ids, meta, row2tok);

  if (ws_size >= need) {
    short* Pg = (short*)((char*)d_ws + 32768);
    short* Pu = Pg + wMatShorts;
    short* Pd = Pu + wMatShorts;
    short* xp = Pd + wMatShorts;
    short* inter = xp + xpShorts;

    convert_gather_kernel<<<4096, 256, 0, stream>>>(gateW, upW, hidden,
                                                    row2tok, Pg, Pu, xp);
    gemm1_kernel<<<512, 256, 0, stream>>>(xp, Pg, Pu, downW, Pd, inter);
    gemm2_kernel<<<512, 256, 0, stream>>>(inter, Pd, row2tok, out);
  } else {
    short* xperm = (short*)((char*)d_ws + 32768);
    short* inter = xperm + (size_t)NROWS * H_DIM;

    gather_fb_kernel<<<NROWS, 256, 0, stream>>>(hidden, row2tok, xperm);
    gemm1_fb_kernel<<<dim3(36, EI_DIM / 128), 256, 0, stream>>>(
        xperm, gateW, upW, meta, inter);
    gemm2_fb_kernel<<<dim3(36, H_DIM / 128), 256, 0, stream>>>(
        inter, downW, meta, row2tok, out);
  }
}